// Round 10
// baseline (3854.390 us; speedup 1.0000x reference)
//
#include <hip/hip_runtime.h>
#include <hip/hip_bf16.h>
#include <stdint.h>

typedef __bf16 bf16_t;
typedef __bf16 bf16x8 __attribute__((ext_vector_type(8)));
typedef float  f32x4  __attribute__((ext_vector_type(4)));
typedef uint32_t u32x4 __attribute__((ext_vector_type(4)));

#define T_STEPS 512
#define BATCH   64
#define EMBD    512
#define HID     1024
#define MROWS   (T_STEPS * BATCH)   // 32768
#define HSLOT   (BATCH * HID)       // 65536 elems = 131072 B per h slot
#define NBLK    64                  // LSTM blocks; each owns 16 hidden units (64 gate rows)
#define UNITS   16

// ws layout
#define OFF_FLAGS 0u                     // 64 flags, 256B apart (16KB; 32KB reserved)
#define OFF_RING  32768u                 // h ring: 2 slots * 128KB
#define OFF_WIP   (OFF_RING + 262144u)   // packed W_ih bf16 fragments: 8MB
#define OFF_E     (OFF_WIP + 8388608u)   // e bf16 [T*B][512] = 32MB

// ---------------- embedding gather: e[t*64+b][:] = bf16(emb[x[b][t]]) ----------------
__global__ __launch_bounds__(256) void k_gather(const int* __restrict__ x,
                                                const float* __restrict__ emb,
                                                bf16_t* __restrict__ e) {
  const int row  = blockIdx.x * 4 + (threadIdx.x >> 6);  // t*64+b
  const int lane = threadIdx.x & 63;
  const int t = row >> 6, b = row & 63;
  const int id = x[b * T_STEPS + t];
  const float* src = emb + (size_t)id * EMBD + lane * 8;
  float4 a = *(const float4*)src;
  float4 c = *(const float4*)(src + 4);
  bf16x8 o;
  o[0]=(bf16_t)a.x; o[1]=(bf16_t)a.y; o[2]=(bf16_t)a.z; o[3]=(bf16_t)a.w;
  o[4]=(bf16_t)c.x; o[5]=(bf16_t)c.y; o[6]=(bf16_t)c.z; o[7]=(bf16_t)c.w;
  *(bf16x8*)(e + (size_t)row * EMBD + lane * 8) = o;
}

// ---------------- pack W_ih into per-block MFMA-fragment order (bf16) ----------------
// Consumer (block bb, wave K-half s, step-k kk, tile t, lane) loads 16B at
// wiP[ ((bb*2+s)*8+kk)*2048 + t*512 + lane*8 ]  — fully coalesced, L2-resident.
// Source: Wih[row = t*1024 + bb*16 + (lane&15)][col = s*256 + kk*32 + (lane>>4)*8]
__global__ __launch_bounds__(256) void k_prepwi(const float* __restrict__ Wih,
                                                bf16_t* __restrict__ wiP) {
  const int bid = blockIdx.x;                 // (bb<<4) | (s<<3) | kk
  const int bb = bid >> 4, s = (bid >> 3) & 1, kk = bid & 7;
  const int tid = threadIdx.x;                // t*64 + lane
  const int t = tid >> 6, lane = tid & 63;
  const int l15 = lane & 15, lq = lane >> 4;
  const float* src = Wih + (size_t)(t * HID + bb * UNITS + l15) * EMBD
                   + s * 256 + kk * 32 + lq * 8;
  float4 a = *(const float4*)src;
  float4 b = *(const float4*)(src + 4);
  bf16x8 v;
  v[0]=(bf16_t)a.x; v[1]=(bf16_t)a.y; v[2]=(bf16_t)a.z; v[3]=(bf16_t)a.w;
  v[4]=(bf16_t)b.x; v[5]=(bf16_t)b.y; v[6]=(bf16_t)b.z; v[7]=(bf16_t)b.w;
  *(bf16x8*)(wiP + (size_t)((bb * 2 + s) * 8 + kk) * 2048 + t * 512 + lane * 8) = v;
}

// ---------------- persistent LSTM scan ----------------
// 64 blocks x 512 threads. Block bb owns units [bb*16,bb*16+16) = 64 gate rows.
// 8 waves = K-half s x batch-quarter w4; each wave: [16 batch x 64 gates] over
// its K-half. W_hh in LDS (128KB, XOR-swizzled); W_ih from packed global (L2).
// h ring block-major [blk][batch][unit16], all h traffic sc0sc1.
// Step: e-part -> wave0 polls 64 flags (1/lane) -> sync -> h-part (16 loads
// pipelined into 64 MFMA) -> s=1 publish gb -> sync -> s=0 sum+gates (4 cells/
// thread) -> sync -> wave7: 2KB burst store + drain + flag.
__global__ __launch_bounds__(512, 1) void k_lstm(const float* __restrict__ Whh,
                                                 const bf16_t* __restrict__ wiP,
                                                 const float* __restrict__ bih,
                                                 const float* __restrict__ bhh,
                                                 const bf16_t* __restrict__ e,
                                                 bf16_t* __restrict__ ring,
                                                 int* __restrict__ flags) {
  __shared__ __align__(16) char Ws[131072];  // [64][1024] bf16, XOR-swizzled
  __shared__ float gb[64 * 66];              // K-half-1 partials [batch][64 gates+pad]
  __shared__ float bsh[64];
  __shared__ bf16_t hstage[1024];            // [batch][unit16]
  const int tid = threadIdx.x;
  const int lane = tid & 63;
  const int w = tid >> 6;            // 0..7
  const int s = w >> 2;              // K-half
  const int w4 = w & 3;              // batch quarter
  const int bb = blockIdx.x;
  const int l15 = lane & 15, lq = lane >> 4;
  const int nmask = (l15 & 7) << 4;

  // stage W_hh slice: 64 rows x 1024 f32 -> bf16, swizzled (8192 chunks of 8)
  for (int c0 = tid; c0 < 8192; c0 += 512) {
    int n = c0 >> 7, koff = c0 & 127;
    int grow = (n >> 4) * HID + bb * UNITS + (n & 15);
    const float4* src = (const float4*)(Whh + (size_t)grow * HID + koff * 8);
    float4 a = src[0], b = src[1];
    bf16x8 v;
    v[0]=(bf16_t)a.x; v[1]=(bf16_t)a.y; v[2]=(bf16_t)a.z; v[3]=(bf16_t)a.w;
    v[4]=(bf16_t)b.x; v[5]=(bf16_t)b.y; v[6]=(bf16_t)b.z; v[7]=(bf16_t)b.w;
    *(bf16x8*)(Ws + n * 2048 + ((koff * 16) ^ ((n & 7) << 4))) = v;
  }
  if (tid < 64) {
    int g = (tid >> 4) * HID + bb * UNITS + (tid & 15);
    bsh[tid] = bih[g] + bhh[g];
  }
  __syncthreads();

  float c_st[4] = {0.f, 0.f, 0.f, 0.f};     // s=0 threads: 4 (batch,unit=l15) cells
  const int a_row = w4 * 16 + l15;
  const bf16_t* wiBase = wiP + (size_t)((bb * 2 + s) * 8) * 2048 + lane * 8;
  const char* wr = Ws + l15 * 2048;          // + tile*32768 + swizzled k-offset

  for (int t = 0; t < T_STEPS; ++t) {
    const bf16_t* hp = ring + (size_t)(t & 1) * HSLOT;
    bf16_t* hn = ring + (size_t)((t + 1) & 1) * HSLOT;

    f32x4 acc0 = {0.f,0.f,0.f,0.f}, acc1 = {0.f,0.f,0.f,0.f};
    f32x4 acc2 = {0.f,0.f,0.f,0.f}, acc3 = {0.f,0.f,0.f,0.f};

    // ---- e-part (h-independent; overlaps producer store/flag latency) ----
    {
      const bf16_t* ep = e + ((size_t)t * BATCH + a_row) * EMBD + s * 256 + lq * 8;
      #pragma unroll
      for (int kk = 0; kk < 8; ++kk) {
        bf16x8 a  = *(const bf16x8*)(ep + kk * 32);
        const bf16_t* wb = wiBase + kk * 2048;
        bf16x8 b0 = *(const bf16x8*)(wb);
        bf16x8 b1 = *(const bf16x8*)(wb + 512);
        bf16x8 b2 = *(const bf16x8*)(wb + 1024);
        bf16x8 b3 = *(const bf16x8*)(wb + 1536);
        acc0 = __builtin_amdgcn_mfma_f32_16x16x32_bf16(a, b0, acc0, 0, 0, 0);
        acc1 = __builtin_amdgcn_mfma_f32_16x16x32_bf16(a, b1, acc1, 0, 0, 0);
        acc2 = __builtin_amdgcn_mfma_f32_16x16x32_bf16(a, b2, acc2, 0, 0, 0);
        acc3 = __builtin_amdgcn_mfma_f32_16x16x32_bf16(a, b3, acc3, 0, 0, 0);
      }
    }

    // ---- wave 0: poll 64 flags, one per lane ----
    if (w == 0 && t > 0) {
      bool done;
      do {
        int cv = __hip_atomic_load(flags + lane * 64, __ATOMIC_RELAXED, __HIP_MEMORY_SCOPE_AGENT);
        done = __all(cv >= t);
        if (!done) __builtin_amdgcn_s_sleep(1);
      } while (!done);
    }
    __syncthreads();
    __builtin_amdgcn_sched_barrier(0);

    // ---- h-part: 16 sc0sc1 loads pipelined into 64 MFMA (B-frags from LDS) ----
    bf16x8 hv[16];
    const bf16_t* bp = hp + (size_t)(s * 32 + (lq >> 1)) * 1024 + a_row * 16 + (lq & 1) * 8;
    #pragma unroll
    for (int kk = 0; kk < 16; ++kk) {
      const bf16_t* ad = bp + kk * 2048;
      asm volatile("global_load_dwordx4 %0, %1, off sc0 sc1"
                   : "=v"(hv[kk]) : "v"(ad) : "memory");
    }
    asm volatile("s_waitcnt vmcnt(8)" ::: "memory");
    __builtin_amdgcn_sched_barrier(0);
    #pragma unroll
    for (int kk = 0; kk < 8; ++kk) {
      int off = ((s * 16 + kk) * 64 + lq * 16) ^ nmask;
      bf16x8 b0 = *(const bf16x8*)(wr + off);
      bf16x8 b1 = *(const bf16x8*)(wr + 32768 + off);
      bf16x8 b2 = *(const bf16x8*)(wr + 65536 + off);
      bf16x8 b3 = *(const bf16x8*)(wr + 98304 + off);
      acc0 = __builtin_amdgcn_mfma_f32_16x16x32_bf16(hv[kk], b0, acc0, 0, 0, 0);
      acc1 = __builtin_amdgcn_mfma_f32_16x16x32_bf16(hv[kk], b1, acc1, 0, 0, 0);
      acc2 = __builtin_amdgcn_mfma_f32_16x16x32_bf16(hv[kk], b2, acc2, 0, 0, 0);
      acc3 = __builtin_amdgcn_mfma_f32_16x16x32_bf16(hv[kk], b3, acc3, 0, 0, 0);
    }
    asm volatile("s_waitcnt vmcnt(0)" ::: "memory");
    __builtin_amdgcn_sched_barrier(0);
    #pragma unroll
    for (int kk = 8; kk < 16; ++kk) {
      int off = ((s * 16 + kk) * 64 + lq * 16) ^ nmask;
      bf16x8 b0 = *(const bf16x8*)(wr + off);
      bf16x8 b1 = *(const bf16x8*)(wr + 32768 + off);
      bf16x8 b2 = *(const bf16x8*)(wr + 65536 + off);
      bf16x8 b3 = *(const bf16x8*)(wr + 98304 + off);
      acc0 = __builtin_amdgcn_mfma_f32_16x16x32_bf16(hv[kk], b0, acc0, 0, 0, 0);
      acc1 = __builtin_amdgcn_mfma_f32_16x16x32_bf16(hv[kk], b1, acc1, 0, 0, 0);
      acc2 = __builtin_amdgcn_mfma_f32_16x16x32_bf16(hv[kk], b2, acc2, 0, 0, 0);
      acc3 = __builtin_amdgcn_mfma_f32_16x16x32_bf16(hv[kk], b3, acc3, 0, 0, 0);
    }

    // ---- K-half 1 waves publish partials ----
    if (s == 1) {
      #pragma unroll
      for (int r = 0; r < 4; ++r) {
        int row = (w4 * 16 + lq * 4 + r) * 66;
        gb[row + l15]      = acc0[r];
        gb[row + 16 + l15] = acc1[r];
        gb[row + 32 + l15] = acc2[r];
        gb[row + 48 + l15] = acc3[r];
      }
    }
    __syncthreads();

    // ---- K-half 0 waves: sum + gates (4 cells per thread: batches r, unit l15) ----
    if (s == 0) {
      #pragma unroll
      for (int r = 0; r < 4; ++r) {
        int b = w4 * 16 + lq * 4 + r;
        float gi = acc0[r] + gb[b * 66 + l15]      + bsh[l15];
        float gf = acc1[r] + gb[b * 66 + 16 + l15] + bsh[16 + l15];
        float gg = acc2[r] + gb[b * 66 + 32 + l15] + bsh[32 + l15];
        float go = acc3[r] + gb[b * 66 + 48 + l15] + bsh[48 + l15];
        float i_ = 1.f / (1.f + __expf(-gi));
        float f_ = 1.f / (1.f + __expf(-gf));
        float g_ = 1.f - 2.f / (1.f + __expf(2.f * gg));   // tanh
        float o_ = 1.f / (1.f + __expf(-go));
        c_st[r] = f_ * c_st[r] + i_ * g_;
        hstage[b * 16 + l15] = (bf16_t)(o_ * (1.f - 2.f / (1.f + __expf(2.f * c_st[r]))));
      }
    }
    __syncthreads();

    // ---- wave 7: gather 2KB, burst store, drain, flag store ----
    if (w == 7) {
      u32x4 v0 = *(const u32x4*)(hstage + lane * 16);
      u32x4 v1 = *(const u32x4*)(hstage + lane * 16 + 8);
      bf16_t* dst = hn + (size_t)bb * 1024 + lane * 16;
      asm volatile("global_store_dwordx4 %0, %1, off sc0 sc1"
                   :: "v"(dst), "v"(v0) : "memory");
      asm volatile("global_store_dwordx4 %0, %1, off offset:16 sc0 sc1"
                   :: "v"(dst), "v"(v1) : "memory");
      asm volatile("s_waitcnt vmcnt(0)" ::: "memory");   // h visible at L3
      if (lane == 0)
        __hip_atomic_store(flags + bb * 64, t + 1,
                           __ATOMIC_RELAXED, __HIP_MEMORY_SCOPE_AGENT);
    }
    // other waves run ahead into e-part(t+1); wave 7 rejoins at next poll-sync
  }
}

// ---------------- final FC: out[b][j] = h[b] . fc_w[j] + fc_b[j] ----------------
// h block-major: h[(j>>4)*1024 + b*16 + (j&15)]
__global__ __launch_bounds__(256) void k_fc(const bf16_t* __restrict__ h,
                                            const float* __restrict__ fcw,
                                            const float* __restrict__ fcb,
                                            float* __restrict__ out) {
  __shared__ float hs[HID];
  const int b = blockIdx.x >> 2, js = blockIdx.x & 3;
  const int tid = threadIdx.x;
  #pragma unroll
  for (int i = 0; i < 4; ++i) {
    int j = tid * 4 + i;
    hs[j] = (float)h[((j >> 4) << 10) + b * 16 + (j & 15)];
  }
  __syncthreads();
  int j = js * 256 + tid;
  const float4* wr = (const float4*)(fcw + (size_t)j * HID);
  float s = 0.f;
  for (int k = 0; k < 256; ++k) {
    float4 wv = wr[k];
    s += hs[k * 4] * wv.x + hs[k * 4 + 1] * wv.y + hs[k * 4 + 2] * wv.z + hs[k * 4 + 3] * wv.w;
  }
  out[b * HID + j] = s + fcb[j];
}

extern "C" void kernel_launch(void* const* d_in, const int* in_sizes, int n_in,
                              void* d_out, int out_size, void* d_ws, size_t ws_size,
                              hipStream_t stream) {
  const int*   x   = (const int*)  d_in[0];
  const float* emb = (const float*)d_in[1];
  const float* Wih = (const float*)d_in[2];
  const float* bih = (const float*)d_in[3];
  const float* Whh = (const float*)d_in[4];
  const float* bhh = (const float*)d_in[5];
  const float* fcw = (const float*)d_in[6];
  const float* fcb = (const float*)d_in[7];
  float* out = (float*)d_out;

  char* ws = (char*)d_ws;
  int*    flags = (int*)   (ws + OFF_FLAGS);
  bf16_t* ring  = (bf16_t*)(ws + OFF_RING);
  bf16_t* wiP   = (bf16_t*)(ws + OFF_WIP);
  bf16_t* e_b   = (bf16_t*)(ws + OFF_E);
  bf16_t* hfin  = ring;   // T_STEPS even -> final h in slot 0

  // zero flags + h slot 0 every call (graph-replay safe)
  (void)hipMemsetAsync(ws, 0, OFF_RING + (size_t)HSLOT * sizeof(bf16_t), stream);

  k_gather<<<MROWS / 4, 256, 0, stream>>>(x, emb, e_b);
  k_prepwi<<<NBLK * 16, 256, 0, stream>>>(Wih, wiP);
  k_lstm<<<NBLK, 512, 0, stream>>>(Whh, wiP, bih, bhh, e_b, ring, flags);
  k_fc<<<BATCH * 4, 256, 0, stream>>>(hfin, fcw, fcb, out);
}

// Round 11
// 2385.400 us; speedup vs baseline: 1.6158x; 1.6158x over previous
//
#include <hip/hip_runtime.h>
#include <hip/hip_bf16.h>
#include <stdint.h>

typedef __bf16 bf16_t;
typedef __bf16 bf16x8 __attribute__((ext_vector_type(8)));
typedef float  f32x4  __attribute__((ext_vector_type(4)));
typedef uint32_t u32x4 __attribute__((ext_vector_type(4)));

#define T_STEPS 512
#define BATCH   64
#define EMBD    512
#define HID     1024
#define MROWS   (T_STEPS * BATCH)   // 32768
#define HSLOT   (BATCH * HID)       // 65536 elems = 131072 B per h slot
#define NBLK    128                 // LSTM blocks; each owns 8 hidden units

// ws layout
#define OFF_FLAGS 0u                    // 128 flags, 256B apart = 32KB
#define OFF_RING  32768u                // h ring: 2 slots * 128KB
#define OFF_E     (OFF_RING + 262144u)  // e bf16 [T*B][512] = 32MB

// ---------------- embedding gather: e[t*64+b][:] = bf16(emb[x[b][t]]) ----------------
__global__ __launch_bounds__(256) void k_gather(const int* __restrict__ x,
                                                const float* __restrict__ emb,
                                                bf16_t* __restrict__ e) {
  const int row  = blockIdx.x * 4 + (threadIdx.x >> 6);  // t*64+b
  const int lane = threadIdx.x & 63;
  const int t = row >> 6, b = row & 63;
  const int id = x[b * T_STEPS + t];
  const float* src = emb + (size_t)id * EMBD + lane * 8;
  float4 a = *(const float4*)src;
  float4 c = *(const float4*)(src + 4);
  bf16x8 o;
  o[0]=(bf16_t)a.x; o[1]=(bf16_t)a.y; o[2]=(bf16_t)a.z; o[3]=(bf16_t)a.w;
  o[4]=(bf16_t)c.x; o[5]=(bf16_t)c.y; o[6]=(bf16_t)c.z; o[7]=(bf16_t)c.w;
  *(bf16x8*)(e + (size_t)row * EMBD + lane * 8) = o;
}

// ---------------- persistent LSTM scan (r8 structure + flag signaling) ----------------
// 128 blocks x 512 threads. Block bb owns hidden units [bb*8,bb*8+8) = 32 gate rows.
// 8 waves = K-half s (2) x batch quarter w4 (4). W_hh B-frags hoisted to VGPRs
// once (ZERO LDS on the h critical path); W_ih in LDS (poll-shadowed e-part only).
// h ring block-major [blk][batch][unit8]; producer wave 0: gather 1KB from LDS
// hstage -> ONE sc0sc1 burst store -> vmcnt(0) drain -> plain flag store (t+1)
// to its own 256B line (NO atomic fan-in). Wave 0 polls all 128 flags (2/lane,
// min + __all), __syncthreads releases block. Gates distributed 1/thread.
// gb parity-buffered so waves run ahead one step.
__global__ __launch_bounds__(512, 1) void k_lstm(const float* __restrict__ Whh,
                                                 const float* __restrict__ Wih,
                                                 const float* __restrict__ bih,
                                                 const float* __restrict__ bhh,
                                                 const bf16_t* __restrict__ e,
                                                 bf16_t* __restrict__ ring,
                                                 int* __restrict__ flags) {
  __shared__ __align__(16) char Ws[65536];   // [32][1024] bf16, XOR-swizzled (staging)
  __shared__ __align__(16) char Wi[32768];   // [32][512]  bf16, XOR-swizzled
  __shared__ float gb[2][2][64 * 33];        // [parity][K-half][batch][32 gates]
  __shared__ float bsh[32];
  __shared__ bf16_t hstage[512];             // [batch][unit8]
  const int tid = threadIdx.x;
  const int lane = tid & 63;
  const int w = tid >> 6;            // 0..7
  const int s = w >> 2;              // K-half
  const int w4 = w & 3;              // batch quarter
  const int bb = blockIdx.x;
  const int l15 = lane & 15, lq = lane >> 4;
  const int nmask = (l15 & 7) << 4;

  // stage W_hh slice: 32 rows x 1024 f32->bf16, swizzled
  for (int c0 = tid; c0 < 4096; c0 += 512) {
    int n = c0 >> 7, koff = c0 & 127;
    int grow = (n >> 3) * HID + bb * 8 + (n & 7);
    const float4* src = (const float4*)(Whh + (size_t)grow * HID + koff * 8);
    float4 a = src[0], b = src[1];
    bf16x8 v;
    v[0]=(bf16_t)a.x; v[1]=(bf16_t)a.y; v[2]=(bf16_t)a.z; v[3]=(bf16_t)a.w;
    v[4]=(bf16_t)b.x; v[5]=(bf16_t)b.y; v[6]=(bf16_t)b.z; v[7]=(bf16_t)b.w;
    *(bf16x8*)(Ws + n * 2048 + ((koff * 16) ^ ((n & 7) << 4))) = v;
  }
  // stage W_ih slice: 32 rows x 512
  for (int c0 = tid; c0 < 2048; c0 += 512) {
    int n = c0 >> 6, koff = c0 & 63;
    int grow = (n >> 3) * HID + bb * 8 + (n & 7);
    const float4* src = (const float4*)(Wih + (size_t)grow * EMBD + koff * 8);
    float4 a = src[0], b = src[1];
    bf16x8 v;
    v[0]=(bf16_t)a.x; v[1]=(bf16_t)a.y; v[2]=(bf16_t)a.z; v[3]=(bf16_t)a.w;
    v[4]=(bf16_t)b.x; v[5]=(bf16_t)b.y; v[6]=(bf16_t)b.z; v[7]=(bf16_t)b.w;
    *(bf16x8*)(Wi + n * 1024 + ((koff * 16) ^ ((n & 7) << 4))) = v;
  }
  if (tid < 32) {
    int g = (tid >> 3) * HID + bb * 8 + (tid & 7);
    bsh[tid] = bih[g] + bhh[g];
  }
  __syncthreads();

  // hoist loop-invariant W_hh B-fragments into VGPRs (once)
  bf16x8 wb0[16], wb1[16];
  {
    const char* wr0 = Ws + l15 * 2048;
    const char* wr1 = Ws + (16 + l15) * 2048;
    #pragma unroll
    for (int kk = 0; kk < 16; ++kk) {
      int off = ((s * 16 + kk) * 64 + lq * 16) ^ nmask;
      wb0[kk] = *(const bf16x8*)(wr0 + off);
      wb1[kk] = *(const bf16x8*)(wr1 + off);
    }
  }

  float c_st = 0.f;                         // per-thread (batch,unit) cell state
  const int un = lane & 7;
  const int gbatch = w * 8 + (lane >> 3);
  const int a_row = w4 * 16 + l15;          // batch row for MFMA A-frags
  const char* wi0 = Wi + l15 * 1024;
  const char* wi1 = Wi + (16 + l15) * 1024;

  for (int t = 0; t < T_STEPS; ++t) {
    const bf16_t* hp = ring + (size_t)(t & 1) * HSLOT;
    bf16_t* hn = ring + (size_t)((t + 1) & 1) * HSLOT;
    const int par = t & 1;

    f32x4 acc0 = {0.f, 0.f, 0.f, 0.f};
    f32x4 acc1 = {0.f, 0.f, 0.f, 0.f};

    // ---- e-part (h-independent; overlaps producer store/flag latency) ----
    {
      const bf16_t* ep = e + ((size_t)t * BATCH + a_row) * EMBD + s * 256 + lq * 8;
      #pragma unroll
      for (int kk = 0; kk < 8; ++kk) {
        bf16x8 a  = *(const bf16x8*)(ep + kk * 32);
        int off = ((s * 8 + kk) * 64 + lq * 16) ^ nmask;
        bf16x8 b0 = *(const bf16x8*)(wi0 + off);
        bf16x8 b1 = *(const bf16x8*)(wi1 + off);
        acc0 = __builtin_amdgcn_mfma_f32_16x16x32_bf16(a, b0, acc0, 0, 0, 0);
        acc1 = __builtin_amdgcn_mfma_f32_16x16x32_bf16(a, b1, acc1, 0, 0, 0);
      }
    }

    // ---- wave 0: poll all 128 flags, 2 per lane ----
    if (w == 0 && t > 0) {
      bool done;
      do {
        int c0 = __hip_atomic_load(flags + lane * 64,        __ATOMIC_RELAXED, __HIP_MEMORY_SCOPE_AGENT);
        int c1 = __hip_atomic_load(flags + (64 + lane) * 64, __ATOMIC_RELAXED, __HIP_MEMORY_SCOPE_AGENT);
        done = __all((c0 < c1 ? c0 : c1) >= t);
        if (!done) __builtin_amdgcn_s_sleep(1);
      } while (!done);
    }
    __syncthreads();                      // release all waves into h-part
    __builtin_amdgcn_sched_barrier(0);

    // ---- h-part: 16 sc0sc1 b128 loads, vmcnt-pipelined into 32 reg-B MFMA ----
    bf16x8 hv[16];
    const bf16_t* bp = hp + ((size_t)(s * 64 + lq) << 9) + a_row * 8;
    #pragma unroll
    for (int kk = 0; kk < 16; ++kk) {
      const bf16_t* ad = bp + kk * 2048;     // blk chunk (s*64+kk*4+lq), 512 elems apart
      asm volatile("global_load_dwordx4 %0, %1, off sc0 sc1"
                   : "=v"(hv[kk]) : "v"(ad) : "memory");
    }
    asm volatile("s_waitcnt vmcnt(8)" ::: "memory");
    __builtin_amdgcn_sched_barrier(0);
    #pragma unroll
    for (int kk = 0; kk < 8; ++kk) {
      acc0 = __builtin_amdgcn_mfma_f32_16x16x32_bf16(hv[kk], wb0[kk], acc0, 0, 0, 0);
      acc1 = __builtin_amdgcn_mfma_f32_16x16x32_bf16(hv[kk], wb1[kk], acc1, 0, 0, 0);
    }
    asm volatile("s_waitcnt vmcnt(0)" ::: "memory");
    __builtin_amdgcn_sched_barrier(0);
    #pragma unroll
    for (int kk = 8; kk < 16; ++kk) {
      acc0 = __builtin_amdgcn_mfma_f32_16x16x32_bf16(hv[kk], wb0[kk], acc0, 0, 0, 0);
      acc1 = __builtin_amdgcn_mfma_f32_16x16x32_bf16(hv[kk], wb1[kk], acc1, 0, 0, 0);
    }

    // ---- publish partials, sync ----
    #pragma unroll
    for (int r = 0; r < 4; ++r) {
      int brow = (w4 * 16 + lq * 4 + r) * 33;
      gb[par][s][brow + l15]      = acc0[r];
      gb[par][s][brow + 16 + l15] = acc1[r];
    }
    __syncthreads();

    // ---- gates: distributed, one (batch,unit) per thread ----
    {
      const float* g0 = &gb[par][0][gbatch * 33];
      const float* g1 = &gb[par][1][gbatch * 33];
      float gi = g0[un]      + g1[un]      + bsh[un];
      float gf = g0[8 + un]  + g1[8 + un]  + bsh[8 + un];
      float gg = g0[16 + un] + g1[16 + un] + bsh[16 + un];
      float go = g0[24 + un] + g1[24 + un] + bsh[24 + un];
      float i_ = 1.f / (1.f + __expf(-gi));
      float f_ = 1.f / (1.f + __expf(-gf));
      float g_ = 1.f - 2.f / (1.f + __expf(2.f * gg));   // tanh
      float o_ = 1.f / (1.f + __expf(-go));
      c_st = f_ * c_st + i_ * g_;
      hstage[tid] = (bf16_t)(o_ * (1.f - 2.f / (1.f + __expf(2.f * c_st))));
    }
    __syncthreads();

    // ---- wave 0: gather 1KB, ONE burst store, drain, plain flag store ----
    if (w == 0) {
      u32x4 val = *(const u32x4*)(hstage + lane * 8);
      bf16_t* dst = hn + (size_t)bb * 512 + lane * 8;
      asm volatile("global_store_dwordx4 %0, %1, off sc0 sc1"
                   :: "v"(dst), "v"(val) : "memory");
      asm volatile("s_waitcnt vmcnt(0)" ::: "memory");   // h visible at L3
      if (lane == 0)
        __hip_atomic_store(flags + bb * 64, t + 1,
                           __ATOMIC_RELAXED, __HIP_MEMORY_SCOPE_AGENT);
    }
    // waves run ahead into e-part(t+1); parity gb + monotone flags keep it safe
  }
}

// ---------------- final FC: out[b][j] = h[b] . fc_w[j] + fc_b[j] ----------------
// h is block-major: h[(j>>3)*512 + b*8 + (j&7)]
__global__ __launch_bounds__(256) void k_fc(const bf16_t* __restrict__ h,
                                            const float* __restrict__ fcw,
                                            const float* __restrict__ fcb,
                                            float* __restrict__ out) {
  __shared__ float hs[HID];
  const int b = blockIdx.x >> 2, js = blockIdx.x & 3;
  const int tid = threadIdx.x;
  #pragma unroll
  for (int i = 0; i < 4; ++i) {
    int j = tid * 4 + i;
    hs[j] = (float)h[((j >> 3) << 9) + b * 8 + (j & 7)];
  }
  __syncthreads();
  int j = js * 256 + tid;
  const float4* wr = (const float4*)(fcw + (size_t)j * HID);
  float s = 0.f;
  for (int k = 0; k < 256; ++k) {
    float4 wv = wr[k];
    s += hs[k * 4] * wv.x + hs[k * 4 + 1] * wv.y + hs[k * 4 + 2] * wv.z + hs[k * 4 + 3] * wv.w;
  }
  out[b * HID + j] = s + fcb[j];
}

extern "C" void kernel_launch(void* const* d_in, const int* in_sizes, int n_in,
                              void* d_out, int out_size, void* d_ws, size_t ws_size,
                              hipStream_t stream) {
  const int*   x   = (const int*)  d_in[0];
  const float* emb = (const float*)d_in[1];
  const float* Wih = (const float*)d_in[2];
  const float* bih = (const float*)d_in[3];
  const float* Whh = (const float*)d_in[4];
  const float* bhh = (const float*)d_in[5];
  const float* fcw = (const float*)d_in[6];
  const float* fcb = (const float*)d_in[7];
  float* out = (float*)d_out;

  char* ws = (char*)d_ws;
  int*    flags = (int*)   (ws + OFF_FLAGS);
  bf16_t* ring  = (bf16_t*)(ws + OFF_RING);
  bf16_t* e_b   = (bf16_t*)(ws + OFF_E);
  bf16_t* hfin  = ring;   // T_STEPS even -> final h in slot 0

  // zero flags + h slot 0 every call (graph-replay safe)
  (void)hipMemsetAsync(ws, 0, OFF_RING + (size_t)HSLOT * sizeof(bf16_t), stream);

  k_gather<<<MROWS / 4, 256, 0, stream>>>(x, emb, e_b);
  k_lstm<<<NBLK, 512, 0, stream>>>(Whh, Wih, bih, bhh, e_b, ring, flags);
  k_fc<<<BATCH * 4, 256, 0, stream>>>(hfin, fcw, fcb, out);
}